// Round 8
// baseline (199.175 us; speedup 1.0000x reference)
//
#include <hip/hip_runtime.h>
#include <math.h>

// Problem constants (B, NP, NQ, D) = (4, 256, 256, 512)
#define BB   4
#define NP   256
#define NQ   256
#define DD   512
#define DD4  (DD / 4)

typedef float f32x4 __attribute__((ext_vector_type(4)));

static constexpr float kScale = 1.0f / 22.627417f;  // 1/sqrt(512)

// ---------------------------------------------------------------------------
// Fused kernel, grid.x = 1280 — identical to the round-4 structure (best so
// far, 131.9us) with ONE change: plain stores instead of nontemporal, to A/B
// the hypothesis that the gfx950 `nt` write path caps at ~4.5 TB/s while the
// normal write-back path sustains ~6.8 TB/s (rocclr fill evidence).
//
//  blocks [0, 1024):   type A, one (b,n): gate row in-block (dot512 + block
//                      softmax -> LDS), then streaming gated-combine write.
//  blocks [1024,1280): type B, 4 p-rows of attn/log_attn = softmax(q.k^T/T).
// ---------------------------------------------------------------------------
__global__ __launch_bounds__(256) void fused_qgsa4_kernel(
    const float* __restrict__ q,     // [B, NP, D]
    const float* __restrict__ k,     // [B, NP, D]
    const f32x4* __restrict__ v4,    // [B, NP, DD4]
    const float* __restrict__ qq,    // [B, NQ, D]
    const float* __restrict__ qk,    // [B, NP, D]
    const f32x4* __restrict__ qv4,   // [B, NQ, DD4]
    f32x4* __restrict__ out4,        // [B, NQ, NP, DD4]
    float* __restrict__ attn_out,    // [B, NP, NP]
    float* __restrict__ logattn_out) // [B, NP, NP]
{
    __shared__ __align__(16) float smem[4 * 256];
    __shared__ float red[8];
    const int t = threadIdx.x;

    if (blockIdx.x < (unsigned)(BB * NQ)) {
        // ---------------- type A: gate + streaming write ----------------
        const int bn = blockIdx.x;
        const int b  = bn >> 8;
        const int n  = bn & (NQ - 1);
        const int w  = t >> 6;
        const int l  = t & 63;

        // q_scores[b,n,t] = dot(qq[b,n,:], qk[b,t,:]) * kScale
        float val;
        {
            const f32x4* krow = (const f32x4*)(qk + ((size_t)b * NP + t) * DD);
            const float* qrow = qq + ((size_t)b * NQ + n) * DD;  // wave-uniform
            float acc = 0.f;
            #pragma unroll 8
            for (int d4 = 0; d4 < DD4; ++d4) {
                const f32x4 kv = krow[d4];
                const float* qr = qrow + d4 * 4;
                acc += qr[0] * kv.x + qr[1] * kv.y + qr[2] * kv.z + qr[3] * kv.w;
            }
            val = acc * kScale;
        }

        // Block softmax over 256 values (one per thread) -> gate in LDS.
        float m = val;
        #pragma unroll
        for (int off = 32; off >= 1; off >>= 1) m = fmaxf(m, __shfl_xor(m, off, 64));
        if (l == 0) red[w] = m;
        __syncthreads();
        m = fmaxf(fmaxf(red[0], red[1]), fmaxf(red[2], red[3]));

        const float e = expf(val - m);
        float s = e;
        #pragma unroll
        for (int off = 32; off >= 1; off >>= 1) s += __shfl_xor(s, off, 64);
        if (l == 0) red[4 + w] = s;
        __syncthreads();
        s = (red[4] + red[5]) + (red[6] + red[7]);

        smem[t] = e / s;          // gate[b,n,t]
        __syncthreads();

        // out[b,n,p,:] = gate[p] * (v[b,p,:] + qv[b,n,:])
        const int d4 = t & (DD4 - 1);
        const int po = t >> 7;    // 0 or 1
        const f32x4 qvr = qv4[((size_t)b * NQ + n) * DD4 + d4];
        const f32x4* vcol = v4 + (size_t)b * NP * DD4 + d4;
        f32x4* ocol = out4 + ((size_t)b * NQ + n) * ((size_t)NP * DD4) + d4;

        #pragma unroll 4
        for (int p = po; p < NP; p += 2) {
            const float gpn = smem[p];                 // LDS broadcast
            const f32x4 vv  = vcol[(size_t)p * DD4];
            ocol[(size_t)p * DD4] = (vv + qvr) * gpn;  // plain store (A/B vs NT)
        }
    } else {
        // ---------------- type B: attn / log_attn softmax ----------------
        const int idx = blockIdx.x - BB * NQ;  // 0..255
        const int b   = idx >> 6;
        const int p0  = (idx & 63) * 4;

        const f32x4* krow = (const f32x4*)(k + ((size_t)b * NP + t) * DD);
        const float* qb   = q + ((size_t)b * NP + p0) * DD;   // wave-uniform

        float acc[4] = {0.f, 0.f, 0.f, 0.f};
        #pragma unroll 8
        for (int d4 = 0; d4 < DD4; ++d4) {
            const f32x4 kv = krow[d4];
            #pragma unroll
            for (int r = 0; r < 4; ++r) {
                const float* qr = qb + r * DD + d4 * 4;
                acc[r] += qr[0] * kv.x + qr[1] * kv.y + qr[2] * kv.z + qr[3] * kv.w;
            }
        }

        float (*ss)[256] = (float (*)[256])smem;
        #pragma unroll
        for (int r = 0; r < 4; ++r) ss[r][t] = acc[r] * kScale;
        __syncthreads();

        const int r = t >> 6;
        const int g = t & 63;
        const f32x4 sv = ((const f32x4*)ss[r])[g];

        float m = fmaxf(fmaxf(sv.x, sv.y), fmaxf(sv.z, sv.w));
        #pragma unroll
        for (int off = 32; off >= 1; off >>= 1)
            m = fmaxf(m, __shfl_xor(m, off, 64));

        f32x4 ev;
        ev.x = expf(sv.x - m); ev.y = expf(sv.y - m);
        ev.z = expf(sv.z - m); ev.w = expf(sv.w - m);
        float s = (ev.x + ev.y) + (ev.z + ev.w);
        #pragma unroll
        for (int off = 32; off >= 1; off >>= 1) s += __shfl_xor(s, off, 64);

        const float inv = 1.0f / s;
        const float lse = logf(s);

        const size_t base = ((size_t)b * NP + (p0 + r)) * 256;
        ((f32x4*)(attn_out + base))[g] = ev * inv;
        f32x4 lg;
        lg.x = (sv.x - m) - lse; lg.y = (sv.y - m) - lse;
        lg.z = (sv.z - m) - lse; lg.w = (sv.w - m) - lse;
        ((f32x4*)(logattn_out + base))[g] = lg;
    }
}

extern "C" void kernel_launch(void* const* d_in, const int* in_sizes, int n_in,
                              void* d_out, int out_size, void* d_ws, size_t ws_size,
                              hipStream_t stream) {
    // setup_inputs order: q, k, v, query(unused), query_q, query_k, query_v
    const float* q  = (const float*)d_in[0];
    const float* k  = (const float*)d_in[1];
    const float* v  = (const float*)d_in[2];
    const float* qq = (const float*)d_in[4];
    const float* qk = (const float*)d_in[5];
    const float* qv = (const float*)d_in[6];

    float* out = (float*)d_out;
    const size_t out_elems = (size_t)BB * NQ * NP * DD;          // 134,217,728
    float* attn_out    = out + out_elems;                         // [B,NP,256]
    float* logattn_out = attn_out + (size_t)BB * NP * 256;        // [B,NP,256]

    fused_qgsa4_kernel<<<BB * NQ + 256, 256, 0, stream>>>(
        q, k, (const f32x4*)v, qq, qk, (const f32x4*)qv,
        (f32x4*)out, attn_out, logattn_out);
}

// Round 9
// 134.725 us; speedup vs baseline: 1.4784x; 1.4784x over previous
//
#include <hip/hip_runtime.h>
#include <math.h>

// Problem constants (B, NP, NQ, D) = (4, 256, 256, 512)
#define BB   4
#define NP   256
#define NQ   256
#define DD   512
#define DD4  (DD / 4)

#define NSTORE       1792                  // store blocks (grid-stride)
#define TOTAL_CHUNKS 131072                // (B*NQ*NP*DD4)/256 4KB slabs

typedef float f32x4 __attribute__((ext_vector_type(4)));

static constexpr float kScale = 1.0f / 22.627417f;  // 1/sqrt(512)

// ---------------------------------------------------------------------------
// Launch 1: gate table. 4 softmax rows per block of q_scores = qq.qk^T / T,
// written to ws[b][n][p] (1 MB). Grid (64, 4).
// ---------------------------------------------------------------------------
__global__ __launch_bounds__(256) void gate_kernel(
    const float* __restrict__ qq,    // [B, NQ, D]
    const float* __restrict__ qk,    // [B, NP, D]
    float* __restrict__ gws)         // [B, NQ, NP]
{
    const int b  = blockIdx.y;
    const int n0 = blockIdx.x * 4;
    const int t  = threadIdx.x;

    const f32x4* krow = (const f32x4*)(qk + ((size_t)b * NP + t) * DD);
    const float* qb   = qq + ((size_t)b * NQ + n0) * DD;   // wave-uniform

    float acc[4] = {0.f, 0.f, 0.f, 0.f};
    #pragma unroll 8
    for (int d4 = 0; d4 < DD4; ++d4) {
        const f32x4 kv = krow[d4];
        #pragma unroll
        for (int r = 0; r < 4; ++r) {
            const float* qr = qb + r * DD + d4 * 4;
            acc[r] += qr[0] * kv.x + qr[1] * kv.y + qr[2] * kv.z + qr[3] * kv.w;
        }
    }

    __shared__ __align__(16) float ss[4][256];
    #pragma unroll
    for (int r = 0; r < 4; ++r) ss[r][t] = acc[r] * kScale;
    __syncthreads();

    const int r = t >> 6;
    const int g = t & 63;
    const f32x4 sv = ((const f32x4*)ss[r])[g];

    float m = fmaxf(fmaxf(sv.x, sv.y), fmaxf(sv.z, sv.w));
    #pragma unroll
    for (int off = 32; off >= 1; off >>= 1) m = fmaxf(m, __shfl_xor(m, off, 64));

    f32x4 ev;
    ev.x = expf(sv.x - m); ev.y = expf(sv.y - m);
    ev.z = expf(sv.z - m); ev.w = expf(sv.w - m);
    float s = (ev.x + ev.y) + (ev.z + ev.w);
    #pragma unroll
    for (int off = 32; off >= 1; off >>= 1) s += __shfl_xor(s, off, 64);

    ((f32x4*)(gws + ((size_t)b * NQ + n0 + r) * NP))[g] = ev * (1.0f / s);
}

// ---------------------------------------------------------------------------
// Launch 2, grid.x = NSTORE + 256:
//  blocks [0, NSTORE):  sweeping store machine. Grid-stride over linear 4KB
//    slabs of out — at any instant the active write window is ONE contiguous
//    ~7MB region sweeping forward (rocclr-fill pattern, max DRAM page hits).
//    Slab c covers out4[c*256 .. c*256+255]: b=c>>15, n=(c>>7)&255,
//    p=(2c+(t>>7))&255, d4=t&127. v/qv reads are L2-hits, gate is a
//    wave-uniform s_load from ws.
//  blocks [NSTORE, +256): attn/log_attn = softmax(q.k^T/T), 4 rows each.
// ---------------------------------------------------------------------------
__global__ __launch_bounds__(256) void store_kernel(
    const float* __restrict__ q,     // [B, NP, D]
    const float* __restrict__ k,     // [B, NP, D]
    const f32x4* __restrict__ v4,    // [B, NP, DD4]
    const f32x4* __restrict__ qv4,   // [B, NQ, DD4]
    const float* __restrict__ gws,   // [B, NQ, NP]
    f32x4* __restrict__ out4,        // [B, NQ, NP, DD4]
    float* __restrict__ attn_out,    // [B, NP, NP]
    float* __restrict__ logattn_out) // [B, NP, NP]
{
    const int t = threadIdx.x;

    if (blockIdx.x < (unsigned)NSTORE) {
        const int h  = t >> 7;            // 0/1: which p of the slab
        const int d4 = t & (DD4 - 1);

        for (int c = blockIdx.x; c < TOTAL_CHUNKS; c += NSTORE) {
            const int b = c >> 15;
            const int n = (c >> 7) & 255;
            const int p = (2 * c + h) & 255;

            int gidx = (((b << 8) + n) << 8) + p;
            gidx = __builtin_amdgcn_readfirstlane(gidx);   // force s_load
            const float gpn = gws[gidx];

            const f32x4 vv  = v4[(((size_t)(b << 8) + p) << 7) + d4];
            const f32x4 qvv = qv4[(((size_t)(b << 8) + n) << 7) + d4];
            __builtin_nontemporal_store((vv + qvv) * gpn,
                                        out4 + ((size_t)c << 8) + t);
        }
    } else {
        // ---------------- type B: attn / log_attn softmax ----------------
        const int idx = blockIdx.x - NSTORE;   // 0..255
        const int b   = idx >> 6;
        const int p0  = (idx & 63) * 4;

        const f32x4* krow = (const f32x4*)(k + ((size_t)b * NP + t) * DD);
        const float* qb   = q + ((size_t)b * NP + p0) * DD;   // wave-uniform

        float acc[4] = {0.f, 0.f, 0.f, 0.f};
        #pragma unroll 8
        for (int d4 = 0; d4 < DD4; ++d4) {
            const f32x4 kv = krow[d4];
            #pragma unroll
            for (int r = 0; r < 4; ++r) {
                const float* qr = qb + r * DD + d4 * 4;
                acc[r] += qr[0] * kv.x + qr[1] * kv.y + qr[2] * kv.z + qr[3] * kv.w;
            }
        }

        __shared__ __align__(16) float ss[4][256];
        #pragma unroll
        for (int r = 0; r < 4; ++r) ss[r][t] = acc[r] * kScale;
        __syncthreads();

        const int r = t >> 6;
        const int g = t & 63;
        const f32x4 sv = ((const f32x4*)ss[r])[g];

        float m = fmaxf(fmaxf(sv.x, sv.y), fmaxf(sv.z, sv.w));
        #pragma unroll
        for (int off = 32; off >= 1; off >>= 1)
            m = fmaxf(m, __shfl_xor(m, off, 64));

        f32x4 ev;
        ev.x = expf(sv.x - m); ev.y = expf(sv.y - m);
        ev.z = expf(sv.z - m); ev.w = expf(sv.w - m);
        float s = (ev.x + ev.y) + (ev.z + ev.w);
        #pragma unroll
        for (int off = 32; off >= 1; off >>= 1) s += __shfl_xor(s, off, 64);

        const float inv = 1.0f / s;
        const float lse = logf(s);

        const size_t base = ((size_t)b * NP + (p0 + r)) * 256;
        ((f32x4*)(attn_out + base))[g] = ev * inv;
        f32x4 lg;
        lg.x = (sv.x - m) - lse; lg.y = (sv.y - m) - lse;
        lg.z = (sv.z - m) - lse; lg.w = (sv.w - m) - lse;
        ((f32x4*)(logattn_out + base))[g] = lg;
    }
}

extern "C" void kernel_launch(void* const* d_in, const int* in_sizes, int n_in,
                              void* d_out, int out_size, void* d_ws, size_t ws_size,
                              hipStream_t stream) {
    // setup_inputs order: q, k, v, query(unused), query_q, query_k, query_v
    const float* q  = (const float*)d_in[0];
    const float* k  = (const float*)d_in[1];
    const float* v  = (const float*)d_in[2];
    const float* qq = (const float*)d_in[4];
    const float* qk = (const float*)d_in[5];
    const float* qv = (const float*)d_in[6];

    float* out = (float*)d_out;
    const size_t out_elems = (size_t)BB * NQ * NP * DD;          // 134,217,728
    float* attn_out    = out + out_elems;                         // [B,NP,256]
    float* logattn_out = attn_out + (size_t)BB * NP * 256;        // [B,NP,256]

    float* gws = (float*)d_ws;       // needs 4*256*256*4 = 1 MB of scratch

    // 1) gate table -> workspace.
    gate_kernel<<<dim3(NQ / 4, BB), 256, 0, stream>>>(qq, qk, gws);

    // 2) sweeping gated-combine write + (hidden) attn/log_attn softmax.
    store_kernel<<<NSTORE + 256, 256, 0, stream>>>(
        q, k, (const f32x4*)v, (const f32x4*)qv, gws,
        (f32x4*)out, attn_out, logattn_out);
}